// Round 4
// baseline (17.696 us; speedup 1.0000x reference)
//
#include <hip/hip_runtime.h>

// Problem constants (fixed by setup_inputs):
//   N_TRAILS=256, N_STEPS=16, N_NODES=4096
//   trail edges: e = i*256+t (i<15), u=e, v=e+256
//   dev edges:   e = 3840 + i*255 + t (t<255), u=i*256+t, v=u+1
#define N_TRAILS 256
#define N_STEPS 16
#define N_NODES 4096
#define N_TRAIL_E 3840
#define N_DEV_E 4080
#define N_EDGES 7920

// d_out layout (f32, concatenated return order):
//   xyz (4096,3) | reactions (4096,3) | lengths (7920,1) | loads (4096,3) | forces (7920,1)
#define OFF_XYZ 0
#define OFF_REACT 12288
#define OFF_LEN 24576
#define OFF_LOADS 32496
#define OFF_FORCES 44784

// 8 scan waves (blocks 0..7): wave w owns core trails [32w, 32w+32) in lanes
// 16..47, plus a 16-trail halo on each side. The trail coupling is a +-1
// stencil per step, so after 16 steps the core lanes are exact while edge /
// wraparound corruption advances at most 15 lanes inward. No LDS, no
// __syncthreads; neighbors via in-wave shfl.
// Blocks 8..55: float4 copy/zero segments (all offsets 16B-aligned).
__global__ __launch_bounds__(64, 1) void cem_fused(
    const float* __restrict__ xyz0,
    const float* __restrict__ loads,
    const float* __restrict__ lengths0,
    const float* __restrict__ planes,
    const float* __restrict__ forces0,
    float* __restrict__ out) {
    const int lane = threadIdx.x;
    const int b = blockIdx.x;

    if (b >= 8) {
        // ---- float4 copy/zero blocks, idx4 in [0, 3072) ----
        int idx4 = (b - 8) * 64 + lane;
        float4* o4 = (float4*)out;
        // zero reactions rows 0..14 (row 15 written by scan blocks): 2880 f4
        if (idx4 < (N_TRAIL_E * 3 / 4))
            o4[OFF_REACT / 4 + idx4] = make_float4(0.f, 0.f, 0.f, 0.f);
        // loads passthrough: 3072 f4
        if (idx4 < (N_NODES * 3 / 4))
            o4[OFF_LOADS / 4 + idx4] = ((const float4*)loads)[idx4];
        // deviation-edge forces passthrough: 1020 f4
        if (idx4 < (N_DEV_E / 4))
            o4[(OFF_FORCES + N_TRAIL_E) / 4 + idx4] =
                ((const float4*)(forces0 + N_TRAIL_E))[idx4];
        return;
    }

    // ---- scan blocks ----
    const int tr_raw = 32 * b - 16 + lane;                  // may be out of [0,256)
    const int tr = min(max(tr_raw, 0), N_TRAILS - 1);       // clamped load index
    const bool core = (lane >= 16) && (lane < 48);
    const bool has_left = (tr_raw > 0);
    const bool has_right = (tr_raw < N_TRAILS - 1);

    // Preload all 16 steps' per-trail data into registers (latency paid once,
    // overlapped). ~192 floats/lane; __launch_bounds__(64,1) permits 512 VGPR.
    float pl[N_STEPS][3];   // loads[n]
    float pp[N_STEPS][6];   // planes[n]
    float l0[N_STEPS];      // lengths0[n]
    float fL[N_STEPS];      // forces0[left dev edge]
    float fR[N_STEPS];      // forces0[right dev edge]
#pragma unroll
    for (int i = 0; i < N_STEPS; ++i) {
        const int n = i * N_TRAILS + tr;
        pl[i][0] = loads[3 * n + 0];
        pl[i][1] = loads[3 * n + 1];
        pl[i][2] = loads[3 * n + 2];
        const float2* p2 = (const float2*)(planes + 6 * n);  // 8B-aligned
        float2 a = p2[0], bb = p2[1], c = p2[2];
        pp[i][0] = a.x;  pp[i][1] = a.y;  pp[i][2] = bb.x;
        pp[i][3] = bb.y; pp[i][4] = c.x;  pp[i][5] = c.y;
        l0[i] = lengths0[n];
        const int ebase = N_TRAIL_E + i * (N_TRAILS - 1);
        fL[i] = forces0[ebase + max(tr - 1, 0)];         // unused unless has_left
        fR[i] = forces0[ebase + min(tr, N_TRAILS - 2)];  // unused unless has_right
    }

    // row 0 positions = xyz0[trail]
    float px = xyz0[3 * tr + 0];
    float py = xyz0[3 * tr + 1];
    float pz = xyz0[3 * tr + 2];
    float rx = 0.f, ry = 0.f, rz = 0.f;  // residuals carry

#pragma unroll
    for (int i = 0; i < N_STEPS; ++i) {
        const int n = i * N_TRAILS + tr_raw;

        // xyz[row i] = position carried into this step (pre-update)
        if (core) {
            out[OFF_XYZ + 3 * n + 0] = px;
            out[OFF_XYZ + 3 * n + 1] = py;
            out[OFF_XYZ + 3 * n + 2] = pz;
        }

        // neighbor positions via in-wave shuffle (wraps at lane 0/63: halo-only)
        float lx = __shfl(px, lane - 1), ly = __shfl(py, lane - 1), lz = __shfl(pz, lane - 1);
        float qx = __shfl(px, lane + 1), qy = __shfl(py, lane + 1), qz = __shfl(pz, lane + 1);

        // deviation from the (at most 2) incident deviation edges of row i
        float dx = 0.f, dy = 0.f, dz = 0.f;
        if (has_left) {
            // edge eL: (i,t-1)->(i,t); incidence[eL,n] = -1; vec = x[t]-x[t-1]
            float vx = px - lx, vy = py - ly, vz = pz - lz;
            float s = vx * vx + vy * vy + vz * vz;
            float inv = (s == 0.f) ? 1.f : (1.f / sqrtf(s));
            float f = fL[i];
            dx -= f * (vx * inv);
            dy -= f * (vy * inv);
            dz -= f * (vz * inv);
        }
        if (has_right) {
            // edge eR: (i,t)->(i,t+1); incidence[eR,n] = +1; vec = x[t+1]-x[t]
            float vx = qx - px, vy = qy - py, vz = qz - pz;
            float s = vx * vx + vy * vy + vz * vz;
            float inv = (s == 0.f) ? 1.f : (1.f / sqrtf(s));
            float f = fR[i];
            dx += f * (vx * inv);
            dy += f * (vy * inv);
            dz += f * (vz * inv);
            // dev-edge length: row-i positions ARE final xyz for row i
            if (core) out[OFF_LEN + N_TRAIL_E + i * (N_TRAILS - 1) + tr_raw] = sqrtf(s);
        }

        // residuals = residuals - deviation - loads[n]
        rx = rx - dx - pl[i][0];
        ry = ry - dy - pl[i][1];
        rz = rz - dz - pl[i][2];

        // plane logic
        float ox = pp[i][0], oy = pp[i][1], oz = pp[i][2];
        float nx = pp[i][3], ny = pp[i][4], nz = pp[i][5];
        bool zero_n = (fabsf(nx) <= 1e-8f) && (fabsf(ny) <= 1e-8f) && (fabsf(nz) <= 1e-8f);
        if (zero_n) { nx = 1.f; ny = 1.f; nz = 1.f; }
        float cos_nop = zero_n ? 0.f
                               : (nx * (ox - px) + ny * (oy - py) + nz * (oz - pz));
        bool zero_r = (fabsf(rx) <= 1e-8f) && (fabsf(ry) <= 1e-8f) && (fabsf(rz) <= 1e-8f);
        float rsx = zero_r ? 1.f : rx;
        float rsy = zero_r ? 1.f : ry;
        float rsz = zero_r ? 1.f : rz;
        float s2 = rsx * rsx + rsy * rsy + rsz * rsz;
        float inv2 = (s2 == 0.f) ? 1.f : (1.f / sqrtf(s2));
        float denom = nx * (rsx * inv2) + ny * (rsy * inv2) + nz * (rsz * inv2);
        float len_plane = zero_r ? 0.f : (cos_nop / denom);
        float l0v = l0[i];
        float L = (l0v != 0.f) ? l0v : len_plane;

        float sr = rx * rx + ry * ry + rz * rz;
        float rn = sqrtf(sr);
        if (i < N_STEPS - 1) {
            if (core) {
                // trail edge e = i*256+t: force = |res| * sign(L>=0)
                out[OFF_FORCES + i * N_TRAILS + tr_raw] = rn * ((L < 0.f) ? -1.f : 1.f);
                // trail edge length = |xyz_next - xyz| = |L| (0 if res == 0)
                out[OFF_LEN + i * N_TRAILS + tr_raw] = (sr == 0.f) ? 0.f : fabsf(L);
            }
        } else if (core) {
            // reactions[row 15] = final residuals
            out[OFF_REACT + 3 * n + 0] = rx;
            out[OFF_REACT + 3 * n + 1] = ry;
            out[OFF_REACT + 3 * n + 2] = rz;
        }

        // xyz_next = xyz + L * safe_normalize(residuals)
        float invr = (sr == 0.f) ? 1.f : (1.f / sqrtf(sr));
        px = px + L * (rx * invr);
        py = py + L * (ry * invr);
        pz = pz + L * (rz * invr);
    }
}

extern "C" void kernel_launch(void* const* d_in, const int* in_sizes, int n_in,
                              void* d_out, int out_size, void* d_ws, size_t ws_size,
                              hipStream_t stream) {
    const float* xyz0     = (const float*)d_in[0];
    const float* loads    = (const float*)d_in[1];
    const float* lengths0 = (const float*)d_in[2];
    const float* planes   = (const float*)d_in[3];
    const float* forces0  = (const float*)d_in[4];
    float* out = (float*)d_out;

    // blocks 0..7: independent 64-lane scan waves (32 core trails each)
    // blocks 8..55: float4 copy/zero segments (48*64 = 3072 f4 covers largest)
    cem_fused<<<56, 64, 0, stream>>>(xyz0, loads, lengths0, planes, forces0, out);
}